// Round 4
// baseline (117.482 us; speedup 1.0000x reference)
//
#include <hip/hip_runtime.h>
#include <cstdint>
#include <cstddef>

typedef __attribute__((ext_vector_type(4))) int i32x4;
typedef __attribute__((ext_vector_type(4))) float f32x4;

#define XSTRIDE 848   // LDS bytes/row for xq: 53*16 -> ~2-way bank alias (free)
#define HSTRIDE 272   // LDS bytes/row for hq: 17*16
#define NTILE 4       // 64-row tiles per block

static __device__ __forceinline__ f32x4 ntload(const float* p) {
    return __builtin_nontemporal_load((const f32x4*)p);
}

static __device__ __forceinline__ int q4ri(f32x4 v, float ri) {
    float a = fminf(fmaxf(rintf(v.x * ri), -127.f), 127.f);
    float b = fminf(fmaxf(rintf(v.y * ri), -127.f), 127.f);
    float c = fminf(fmaxf(rintf(v.z * ri), -127.f), 127.f);
    float d = fminf(fmaxf(rintf(v.w * ri), -127.f), 127.f);
    return ((int)a & 255) | (((int)b & 255) << 8) | (((int)c & 255) << 16) | (((int)d & 255) << 24);
}
static __device__ __forceinline__ int q4div(f32x4 v, float s) {
    float a = fminf(fmaxf(rintf(v.x / s), -127.f), 127.f);
    float b = fminf(fmaxf(rintf(v.y / s), -127.f), 127.f);
    float c = fminf(fmaxf(rintf(v.z / s), -127.f), 127.f);
    float d = fminf(fmaxf(rintf(v.w / s), -127.f), 127.f);
    return ((int)a & 255) | (((int)b & 255) << 8) | (((int)c & 255) << 16) | (((int)d & 255) << 24);
}
static __device__ __forceinline__ float max4abs(f32x4 v) {
    return fmaxf(fmaxf(fabsf(v.x), fabsf(v.y)), fmaxf(fabsf(v.z), fabsf(v.w)));
}

// ---------------- weight quantization (tiny, runs once per call) --------------
__global__ __launch_bounds__(64) void quantW(const float* __restrict__ W1,
                                             const float* __restrict__ W2,
                                             int8_t* __restrict__ W1q, float* __restrict__ W1s,
                                             int8_t* __restrict__ W2q, float* __restrict__ W2s) {
    const int l = threadIdx.x;
    const int b = blockIdx.x;
    if (b < 256) {
        const float* wr = W1 + (size_t)b * 784;
        f32x4 v0 = *(const f32x4*)(wr + 4 * l);
        f32x4 v1 = *(const f32x4*)(wr + 4 * (l + 64));
        f32x4 v2 = *(const f32x4*)(wr + 4 * (l + 128));
        f32x4 v3 = (f32x4){0.f, 0.f, 0.f, 0.f};
        if (l < 4) v3 = *(const f32x4*)(wr + 4 * (192 + l));
        float m = fmaxf(fmaxf(max4abs(v0), max4abs(v1)), fmaxf(max4abs(v2), max4abs(v3)));
        #pragma unroll
        for (int off = 32; off >= 1; off >>= 1) m = fmaxf(m, __shfl_xor(m, off));
        float s = (m == 0.f) ? 1.f : m / 127.f;
        int* ow = (int*)(W1q + (size_t)b * 832);
        ow[l] = q4div(v0, s);
        ow[l + 64] = q4div(v1, s);
        ow[l + 128] = q4div(v2, s);
        if (l < 4) ow[192 + l] = q4div(v3, s);
        if (l >= 16 && l < 28) ow[196 + (l - 16)] = 0;
        if (l == 0) W1s[b] = s;
    } else {
        const int r = b - 256;
        int* ow = (int*)(W2q + (size_t)r * 256);
        if (r < 10) {
            f32x4 v0 = *(const f32x4*)(W2 + (size_t)r * 256 + 4 * l);
            float m = max4abs(v0);
            #pragma unroll
            for (int off = 32; off >= 1; off >>= 1) m = fmaxf(m, __shfl_xor(m, off));
            float s = (m == 0.f) ? 1.f : m / 127.f;
            ow[l] = q4div(v0, s);
            if (l == 0) W2s[r] = s;
        } else {
            ow[l] = 0;
            if (l == 0) W2s[r] = 1.f;
        }
    }
}

// ---------------- fused MLP, tile-level producer/consumer pipeline ------------
// 8 waves, 1 block/CU (LDS ~130 KB). Each block: 4 tiles of 64 rows.
// Per iter: issue next tile's global loads (196 KB in flight) -> compute
// current tile from LDS -> drain + quantize next tile into the other buffer.
__global__ __launch_bounds__(512, 2) void fused_mlp(
    const float* __restrict__ x,
    const int8_t* __restrict__ W1q, const float* __restrict__ W1s, const float* __restrict__ b1,
    const int8_t* __restrict__ W2q, const float* __restrict__ W2s, const float* __restrict__ b2,
    float* __restrict__ out)
{
    __shared__ __align__(16) int8_t xq[2][64 * XSTRIDE];   // 108544 B
    __shared__ __align__(16) int8_t hq[64 * HSTRIDE];      // 17408 B
    __shared__ float sxs[2][64];
    __shared__ float hpart[8][64];
    __shared__ float s2s[64];
    __shared__ float b1s[256], w1ss[256];
    __shared__ float b2s[16], w2ss[16];

    const int t = threadIdx.x;
    const int l = t & 63;
    const int w = t >> 6;            // wave 0..7
    const int g = l >> 4;            // 16-lane group 0..3
    const int lr = l & 15;
    const size_t blk0 = (size_t)blockIdx.x * (64 * NTILE);
    const int rbase = w * 8;         // this wave's 8 rows within a tile

    if (t < 256) { b1s[t] = b1[t]; w1ss[t] = W1s[t]; }
    if (t < 16) { w2ss[t] = W2s[t]; b2s[t] = (t < 10) ? b2[t] : 0.f; }

    f32x4 R[8][3];   // 96 VGPRs: rows rbase..rbase+7, chunks l, l+64, l+128
    f32x4 Rt;        // lanes 0..31: tail chunk 192+(l&3) of row rbase+(l>>2)

    // ---- issue loads for tile 0 ----
    {
        const float* xb = x + (blk0 + rbase) * 784;
        #pragma unroll
        for (int r = 0; r < 8; ++r) {
            R[r][0] = ntload(xb + (size_t)r * 784 + 4 * l);
            R[r][1] = ntload(xb + (size_t)r * 784 + 4 * (l + 64));
            R[r][2] = ntload(xb + (size_t)r * 784 + 4 * (l + 128));
        }
        if (l < 32) Rt = ntload(xb + (size_t)(l >> 2) * 784 + 4 * (192 + (l & 3)));
    }

    // ---- quantize tile 0 into xq[0] ----
    #pragma unroll
    for (int r = 0; r < 8; ++r) {
        float m = fmaxf(max4abs(R[r][0]), fmaxf(max4abs(R[r][1]), max4abs(R[r][2])));
        if ((l >> 2) == r) m = fmaxf(m, max4abs(Rt));
        #pragma unroll
        for (int off = 32; off >= 1; off >>= 1) m = fmaxf(m, __shfl_xor(m, off));
        float s = (m == 0.f) ? 1.f : m / 127.f;
        float ri = 1.f / s;
        int* xw = (int*)(xq[0] + (rbase + r) * XSTRIDE);
        xw[l] = q4ri(R[r][0], ri);
        xw[l + 64] = q4ri(R[r][1], ri);
        xw[l + 128] = q4ri(R[r][2], ri);
        if ((l >> 2) == r) xw[192 + (l & 3)] = q4ri(Rt, ri);
        if (l >= 16 && l < 28) xw[196 + (l - 16)] = 0;   // zero K-pad dwords 196..207
        if (l == 0) sxs[0][rbase + r] = s;
    }
    __syncthreads();

    for (int tt = 0; tt < NTILE; ++tt) {
        const int db = tt & 1;
        const size_t row0 = blk0 + (size_t)tt * 64;

        // ---- issue loads for tile tt+1 (stay in flight across the compute) ----
        if (tt + 1 < NTILE) {
            const float* xb = x + (row0 + 64 + rbase) * 784;
            #pragma unroll
            for (int r = 0; r < 8; ++r) {
                R[r][0] = ntload(xb + (size_t)r * 784 + 4 * l);
                R[r][1] = ntload(xb + (size_t)r * 784 + 4 * (l + 64));
                R[r][2] = ntload(xb + (size_t)r * 784 + 4 * (l + 128));
            }
            if (l < 32) Rt = ntload(xb + (size_t)(l >> 2) * 784 + 4 * (192 + (l & 3)));
        }
        __builtin_amdgcn_sched_barrier(0);   // keep load issue above the GEMM

        // ---- layer-1 GEMM: wave w owns cols w*32..w*32+31, all 64 rows ----
        i32x4 acc[4][2];
        #pragma unroll
        for (int mt = 0; mt < 4; ++mt)
            #pragma unroll
            for (int nt = 0; nt < 2; ++nt)
                acc[mt][nt] = (i32x4){0, 0, 0, 0};

        const int8_t* xbase = xq[db] + lr * XSTRIDE + g * 16;
        const int8_t* wbase = W1q + (size_t)(w * 32 + lr) * 832 + g * 16;

        #pragma unroll
        for (int kk = 0; kk < 13; ++kk) {
            const int ko = kk * 64;
            i32x4 a[4], bv[2];
            #pragma unroll
            for (int mt = 0; mt < 4; ++mt) a[mt] = *(const i32x4*)(xbase + mt * 16 * XSTRIDE + ko);
            #pragma unroll
            for (int nt = 0; nt < 2; ++nt) bv[nt] = *(const i32x4*)(wbase + (size_t)nt * 16 * 832 + ko);
            #pragma unroll
            for (int mt = 0; mt < 4; ++mt)
                #pragma unroll
                for (int nt = 0; nt < 2; ++nt)
                    acc[mt][nt] = __builtin_amdgcn_mfma_i32_16x16x64_i8(a[mt], bv[nt], acc[mt][nt], 0, 0, 0);
        }

        // ---- dequant + bias + relu ----
        float h[4][4][2];
        #pragma unroll
        for (int mt = 0; mt < 4; ++mt)
            #pragma unroll
            for (int nt = 0; nt < 2; ++nt)
                #pragma unroll
                for (int r = 0; r < 4; ++r) {
                    const int rowl = mt * 16 + g * 4 + r;
                    const int coll = w * 32 + nt * 16 + lr;
                    float v = sxs[db][rowl] * w1ss[coll] * (float)acc[mt][nt][r] + b1s[coll];
                    h[mt][r][nt] = fmaxf(v, 0.f);
                }

        // ---- per-row max of h ----
        #pragma unroll
        for (int mt = 0; mt < 4; ++mt)
            #pragma unroll
            for (int r = 0; r < 4; ++r) {
                float m = fmaxf(h[mt][r][0], h[mt][r][1]);
                m = fmaxf(m, __shfl_xor(m, 1));
                m = fmaxf(m, __shfl_xor(m, 2));
                m = fmaxf(m, __shfl_xor(m, 4));
                m = fmaxf(m, __shfl_xor(m, 8));
                if (lr == 0) hpart[w][mt * 16 + g * 4 + r] = m;
            }
        __syncthreads();

        // ---- requantize h into hq ----
        #pragma unroll
        for (int mt = 0; mt < 4; ++mt)
            #pragma unroll
            for (int r = 0; r < 4; ++r) {
                const int rowl = mt * 16 + g * 4 + r;
                float hm = fmaxf(fmaxf(fmaxf(hpart[0][rowl], hpart[1][rowl]),
                                       fmaxf(hpart[2][rowl], hpart[3][rowl])),
                                 fmaxf(fmaxf(hpart[4][rowl], hpart[5][rowl]),
                                       fmaxf(hpart[6][rowl], hpart[7][rowl])));
                float s2 = (hm == 0.f) ? 1.f : hm / 127.f;
                float ri2 = 1.f / s2;
                if (w == 0 && lr == 0) s2s[rowl] = s2;
                #pragma unroll
                for (int nt = 0; nt < 2; ++nt) {
                    float q = fminf(fmaxf(rintf(h[mt][r][nt] * ri2), -127.f), 127.f);
                    hq[rowl * HSTRIDE + w * 32 + nt * 16 + lr] = (int8_t)(int)q;
                }
            }
        __syncthreads();

        // ---- layer-2 GEMM (waves 0..3) + output ----
        if (w < 4) {
            i32x4 acc2 = (i32x4){0, 0, 0, 0};
            const int8_t* hbase = hq + (w * 16 + lr) * HSTRIDE + g * 16;
            const int8_t* w2base = W2q + lr * 256 + g * 16;
            #pragma unroll
            for (int kk = 0; kk < 4; ++kk) {
                i32x4 av = *(const i32x4*)(hbase + kk * 64);
                i32x4 bv = *(const i32x4*)(w2base + kk * 64);
                acc2 = __builtin_amdgcn_mfma_i32_16x16x64_i8(av, bv, acc2, 0, 0, 0);
            }
            if (lr < 10) {
                #pragma unroll
                for (int r = 0; r < 4; ++r) {
                    const int rowl = w * 16 + g * 4 + r;
                    float v = s2s[rowl] * w2ss[lr] * (float)acc2[r] + b2s[lr];
                    __builtin_nontemporal_store(v, &out[(row0 + rowl) * 10 + lr]);
                }
            }
        }

        // ---- drain loads + quantize tile tt+1 into the other buffer ----
        if (tt + 1 < NTILE) {
            const int db2 = db ^ 1;
            #pragma unroll
            for (int r = 0; r < 8; ++r) {
                float m = fmaxf(max4abs(R[r][0]), fmaxf(max4abs(R[r][1]), max4abs(R[r][2])));
                if ((l >> 2) == r) m = fmaxf(m, max4abs(Rt));
                #pragma unroll
                for (int off = 32; off >= 1; off >>= 1) m = fmaxf(m, __shfl_xor(m, off));
                float s = (m == 0.f) ? 1.f : m / 127.f;
                float ri = 1.f / s;
                int* xw = (int*)(xq[db2] + (rbase + r) * XSTRIDE);
                xw[l] = q4ri(R[r][0], ri);
                xw[l + 64] = q4ri(R[r][1], ri);
                xw[l + 128] = q4ri(R[r][2], ri);
                if ((l >> 2) == r) xw[192 + (l & 3)] = q4ri(Rt, ri);
                if (l >= 16 && l < 28) xw[196 + (l - 16)] = 0;
                if (l == 0) sxs[db2][rbase + r] = s;
            }
        }
        __syncthreads();
    }
}

extern "C" void kernel_launch(void* const* d_in, const int* in_sizes, int n_in,
                              void* d_out, int out_size, void* d_ws, size_t ws_size,
                              hipStream_t stream) {
    const float* x  = (const float*)d_in[0];
    const float* W1 = (const float*)d_in[1];
    const float* b1 = (const float*)d_in[2];
    const float* W2 = (const float*)d_in[3];
    const float* b2 = (const float*)d_in[4];
    float* out = (float*)d_out;

    int8_t* ws = (int8_t*)d_ws;
    int8_t* W1q = ws;                            // 256*832   = 212992 B
    float*  W1s = (float*)(ws + 212992);         // 1024 B
    int8_t* W2q = ws + 214016;                   // 4096 B
    float*  W2s = (float*)(ws + 218112);         // 64 B

    quantW<<<272, 64, 0, stream>>>(W1, W2, W1q, W1s, W2q, W2s);
    fused_mlp<<<256, 512, 0, stream>>>(x, W1q, W1s, b1, W2q, W2s, b2, out);
}

// Round 5
// 66.663 us; speedup vs baseline: 1.7623x; 1.7623x over previous
//
#include <hip/hip_runtime.h>
#include <cstdint>
#include <cstddef>

typedef __attribute__((ext_vector_type(4))) int i32x4;
typedef __attribute__((ext_vector_type(4))) float f32x4;

#define BM 32         // rows per block (small tile -> 4 blocks/CU for phase overlap)
#define XSTRIDE 848   // LDS bytes/row for xq: 53*16 -> ~2-way bank alias (free)
#define HSTRIDE 272   // LDS bytes/row for hq: 17*16

static __device__ __forceinline__ int q4ri(f32x4 v, float ri) {
    float a = fminf(fmaxf(rintf(v.x * ri), -127.f), 127.f);
    float b = fminf(fmaxf(rintf(v.y * ri), -127.f), 127.f);
    float c = fminf(fmaxf(rintf(v.z * ri), -127.f), 127.f);
    float d = fminf(fmaxf(rintf(v.w * ri), -127.f), 127.f);
    return ((int)a & 255) | (((int)b & 255) << 8) | (((int)c & 255) << 16) | (((int)d & 255) << 24);
}
static __device__ __forceinline__ int q4div(f32x4 v, float s) {
    float a = fminf(fmaxf(rintf(v.x / s), -127.f), 127.f);
    float b = fminf(fmaxf(rintf(v.y / s), -127.f), 127.f);
    float c = fminf(fmaxf(rintf(v.z / s), -127.f), 127.f);
    float d = fminf(fmaxf(rintf(v.w / s), -127.f), 127.f);
    return ((int)a & 255) | (((int)b & 255) << 8) | (((int)c & 255) << 16) | (((int)d & 255) << 24);
}
static __device__ __forceinline__ float max4abs(f32x4 v) {
    return fmaxf(fmaxf(fabsf(v.x), fabsf(v.y)), fmaxf(fabsf(v.z), fabsf(v.w)));
}

// ---------------- weight quantization (tiny, runs once per call) --------------
__global__ __launch_bounds__(64) void quantW(const float* __restrict__ W1,
                                             const float* __restrict__ W2,
                                             int8_t* __restrict__ W1q, float* __restrict__ W1s,
                                             int8_t* __restrict__ W2q, float* __restrict__ W2s) {
    const int l = threadIdx.x;
    const int b = blockIdx.x;
    if (b < 256) {
        const float* wr = W1 + (size_t)b * 784;
        f32x4 v0 = *(const f32x4*)(wr + 4 * l);
        f32x4 v1 = *(const f32x4*)(wr + 4 * (l + 64));
        f32x4 v2 = *(const f32x4*)(wr + 4 * (l + 128));
        f32x4 v3 = (f32x4){0.f, 0.f, 0.f, 0.f};
        if (l < 4) v3 = *(const f32x4*)(wr + 4 * (192 + l));
        float m = fmaxf(fmaxf(max4abs(v0), max4abs(v1)), fmaxf(max4abs(v2), max4abs(v3)));
        #pragma unroll
        for (int off = 32; off >= 1; off >>= 1) m = fmaxf(m, __shfl_xor(m, off));
        float s = (m == 0.f) ? 1.f : m / 127.f;
        int* ow = (int*)(W1q + (size_t)b * 832);
        ow[l] = q4div(v0, s);
        ow[l + 64] = q4div(v1, s);
        ow[l + 128] = q4div(v2, s);
        if (l < 4) ow[192 + l] = q4div(v3, s);
        if (l >= 16 && l < 28) ow[196 + (l - 16)] = 0;
        if (l == 0) W1s[b] = s;
    } else {
        const int r = b - 256;
        int* ow = (int*)(W2q + (size_t)r * 256);
        if (r < 10) {
            f32x4 v0 = *(const f32x4*)(W2 + (size_t)r * 256 + 4 * l);
            float m = max4abs(v0);
            #pragma unroll
            for (int off = 32; off >= 1; off >>= 1) m = fmaxf(m, __shfl_xor(m, off));
            float s = (m == 0.f) ? 1.f : m / 127.f;
            ow[l] = q4div(v0, s);
            if (l == 0) W2s[r] = s;
        } else {
            ow[l] = 0;
            if (l == 0) W2s[r] = 1.f;
        }
    }
}

// ---------------- fused MLP: quantize x -> GEMM1 -> relu+requant -> GEMM2 ----
// 256 threads (4 waves), BM=32 rows -> LDS ~39 KB -> 4 blocks/CU. Cross-block
// phase overlap keeps HBM streaming while other blocks compute. VGPR capped
// at 128 by __launch_bounds__(256,4); ~110 live regs, no spill expected.
__global__ __launch_bounds__(256, 4) void fused_mlp(
    const float* __restrict__ x,
    const int8_t* __restrict__ W1q, const float* __restrict__ W1s, const float* __restrict__ b1,
    const int8_t* __restrict__ W2q, const float* __restrict__ W2s, const float* __restrict__ b2,
    float* __restrict__ out)
{
    __shared__ __align__(16) int8_t xq[BM * XSTRIDE];   // 27136 B
    __shared__ __align__(16) int8_t hq[BM * HSTRIDE];   //  8704 B
    __shared__ float sxs[BM];
    __shared__ float hpart[4][BM];
    __shared__ float s2s[BM];
    __shared__ float b1s[256], w1ss[256];
    __shared__ float b2s[16], w2ss[16];

    const int t = threadIdx.x;
    const int l = t & 63;
    const int w = t >> 6;            // wave 0..3
    const int g = l >> 4;            // 16-lane group 0..3
    const int lr = l & 15;
    const size_t row0 = (size_t)blockIdx.x * BM;

    // stage small params
    b1s[t] = b1[t];
    w1ss[t] = W1s[t];
    if (t < 16) { w2ss[t] = W2s[t]; b2s[t] = (t < 10) ? b2[t] : 0.f; }

    // ---- phase 1: per-row absmax + quantize x into LDS (x read once) ----
    // wave w handles rows w*8 .. w*8+7
    for (int i = 0; i < 8; ++i) {
        const int row = w * 8 + i;
        const float* xr = x + (row0 + row) * 784;
        f32x4 v0 = *(const f32x4*)(xr + 4 * l);
        f32x4 v1 = *(const f32x4*)(xr + 4 * (l + 64));
        f32x4 v2 = *(const f32x4*)(xr + 4 * (l + 128));
        f32x4 v3 = (f32x4){0.f, 0.f, 0.f, 0.f};
        if (l < 4) v3 = *(const f32x4*)(xr + 4 * (192 + l));
        float m = fmaxf(fmaxf(max4abs(v0), max4abs(v1)), fmaxf(max4abs(v2), max4abs(v3)));
        #pragma unroll
        for (int off = 32; off >= 1; off >>= 1) m = fmaxf(m, __shfl_xor(m, off));
        float s = (m == 0.f) ? 1.f : m / 127.f;
        float ri = 1.f / s;
        int* xw = (int*)(xq + row * XSTRIDE);
        xw[l] = q4ri(v0, ri);
        xw[l + 64] = q4ri(v1, ri);
        xw[l + 128] = q4ri(v2, ri);
        if (l < 4) xw[192 + l] = q4ri(v3, ri);
        if (l >= 16 && l < 32) xw[196 + (l - 16)] = 0;   // zero K-pad bytes 784..847
        if (l == 0) sxs[row] = s;
    }
    __syncthreads();

    // ---- phase 2: layer-1 GEMM. wave w owns cols w*64..w*64+63, rows 0..31 ----
    i32x4 acc[2][4];
    #pragma unroll
    for (int mt = 0; mt < 2; ++mt)
        #pragma unroll
        for (int nt = 0; nt < 4; ++nt)
            acc[mt][nt] = (i32x4){0, 0, 0, 0};

    const int8_t* xbase = xq + lr * XSTRIDE + g * 16;
    const int8_t* wbase = W1q + (size_t)(w * 64 + lr) * 832 + g * 16;

    #pragma unroll
    for (int kk = 0; kk < 13; ++kk) {
        const int ko = kk * 64;
        i32x4 a[2], bv[4];
        #pragma unroll
        for (int mt = 0; mt < 2; ++mt) a[mt] = *(const i32x4*)(xbase + mt * 16 * XSTRIDE + ko);
        #pragma unroll
        for (int nt = 0; nt < 4; ++nt) bv[nt] = *(const i32x4*)(wbase + (size_t)nt * 16 * 832 + ko);
        #pragma unroll
        for (int mt = 0; mt < 2; ++mt)
            #pragma unroll
            for (int nt = 0; nt < 4; ++nt)
                acc[mt][nt] = __builtin_amdgcn_mfma_i32_16x16x64_i8(a[mt], bv[nt], acc[mt][nt], 0, 0, 0);
    }

    // ---- phase 3: dequant + bias + relu (exact: |acc| < 2^24) ----
    float h[2][4][4];   // [mt][reg][nt]
    #pragma unroll
    for (int mt = 0; mt < 2; ++mt)
        #pragma unroll
        for (int nt = 0; nt < 4; ++nt)
            #pragma unroll
            for (int r = 0; r < 4; ++r) {
                const int rowl = mt * 16 + g * 4 + r;
                const int coll = w * 64 + nt * 16 + lr;
                float v = sxs[rowl] * w1ss[coll] * (float)acc[mt][nt][r] + b1s[coll];
                h[mt][r][nt] = fmaxf(v, 0.f);
            }

    // ---- phase 4: per-row max of h (h>=0 so max == absmax) ----
    #pragma unroll
    for (int mt = 0; mt < 2; ++mt)
        #pragma unroll
        for (int r = 0; r < 4; ++r) {
            float m = fmaxf(fmaxf(h[mt][r][0], h[mt][r][1]), fmaxf(h[mt][r][2], h[mt][r][3]));
            m = fmaxf(m, __shfl_xor(m, 1));
            m = fmaxf(m, __shfl_xor(m, 2));
            m = fmaxf(m, __shfl_xor(m, 4));
            m = fmaxf(m, __shfl_xor(m, 8));
            if (lr == 0) hpart[w][mt * 16 + g * 4 + r] = m;
        }
    __syncthreads();

    // ---- phase 5: requantize h into LDS hq ----
    #pragma unroll
    for (int mt = 0; mt < 2; ++mt)
        #pragma unroll
        for (int r = 0; r < 4; ++r) {
            const int rowl = mt * 16 + g * 4 + r;
            float hm = fmaxf(fmaxf(hpart[0][rowl], hpart[1][rowl]),
                             fmaxf(hpart[2][rowl], hpart[3][rowl]));
            float s2 = (hm == 0.f) ? 1.f : hm / 127.f;
            float ri2 = 1.f / s2;
            if (w == 0 && lr == 0) s2s[rowl] = s2;
            #pragma unroll
            for (int nt = 0; nt < 4; ++nt) {
                float q = fminf(fmaxf(rintf(h[mt][r][nt] * ri2), -127.f), 127.f);
                hq[rowl * HSTRIDE + w * 64 + nt * 16 + lr] = (int8_t)(int)q;
            }
        }
    __syncthreads();

    // ---- phase 6+7: layer-2 GEMM (waves 0..1, 16 rows each) + epilogue ----
    if (w < 2) {
        i32x4 acc2 = (i32x4){0, 0, 0, 0};
        const int8_t* hbase = hq + (w * 16 + lr) * HSTRIDE + g * 16;
        const int8_t* w2base = W2q + lr * 256 + g * 16;
        #pragma unroll
        for (int kk = 0; kk < 4; ++kk) {
            i32x4 av = *(const i32x4*)(hbase + kk * 64);
            i32x4 bv = *(const i32x4*)(w2base + kk * 64);
            acc2 = __builtin_amdgcn_mfma_i32_16x16x64_i8(av, bv, acc2, 0, 0, 0);
        }
        if (lr < 10) {
            #pragma unroll
            for (int r = 0; r < 4; ++r) {
                const int rowl = w * 16 + g * 4 + r;
                float v = s2s[rowl] * w2ss[lr] * (float)acc2[r] + b2s[lr];
                out[(row0 + rowl) * 10 + lr] = v;
            }
        }
    }
}

extern "C" void kernel_launch(void* const* d_in, const int* in_sizes, int n_in,
                              void* d_out, int out_size, void* d_ws, size_t ws_size,
                              hipStream_t stream) {
    const float* x  = (const float*)d_in[0];
    const float* W1 = (const float*)d_in[1];
    const float* b1 = (const float*)d_in[2];
    const float* W2 = (const float*)d_in[3];
    const float* b2 = (const float*)d_in[4];
    float* out = (float*)d_out;

    int8_t* ws = (int8_t*)d_ws;
    int8_t* W1q = ws;                            // 256*832   = 212992 B
    float*  W1s = (float*)(ws + 212992);         // 1024 B
    int8_t* W2q = ws + 214016;                   // 4096 B
    float*  W2s = (float*)(ws + 218112);         // 64 B

    quantW<<<272, 64, 0, stream>>>(W1, W2, W1q, W1s, W2q, W2s);
    fused_mlp<<<2048, 256, 0, stream>>>(x, W1q, W1s, b1, W2q, W2s, b2, out);
}